// Round 5
// baseline (540.689 us; speedup 1.0000x reference)
//
#include <hip/hip_runtime.h>
#include <cstdint>
#include <cstddef>

// ---------------- types / helpers ----------------
typedef _Float16 f16x8 __attribute__((ext_vector_type(8)));
typedef _Float16 f16x4 __attribute__((ext_vector_type(4)));
typedef float    f32x4 __attribute__((ext_vector_type(4)));

#define AS_GLOBAL __attribute__((address_space(1)))
#define AS_LDS    __attribute__((address_space(3)))

__device__ __forceinline__ void load16_to_lds(const _Float16* g, _Float16* l) {
    // async global->LDS, 16 B/lane, LDS dest = wave-uniform base + lane*16
    __builtin_amdgcn_global_load_lds((const AS_GLOBAL void*)g, (AS_LDS void*)l, 16, 0, 0);
}

// ---------------- problem constants ----------------
#define BB   2
#define TT   4096
#define DD   768
#define NH   12
#define HDIM 64
#define D3   2304
// softmax in exp2 domain: scale * log2(e), folded into Q at load
#define SC2  (0.125f * 1.44269504088896f)

// ---------------- merged prologue: cast + both transposes + flag zero ----------------
__global__ __launch_bounds__(256) void prep(const float* __restrict__ x,
                                            _Float16* __restrict__ Xh,
                                            const float* __restrict__ Wqkv,
                                            _Float16* __restrict__ Wqkvt,
                                            const float* __restrict__ Wout,
                                            _Float16* __restrict__ Wot,
                                            int* __restrict__ Fl) {
    const int bid = blockIdx.x, tid = threadIdx.x;
    if (bid < 3) Fl[bid * 256 + tid] = 0;     // 768 combine-flags for attn
    if (bid < 6144) {
        const int i = bid * 1024 + tid * 4;
        float4 v = *(const float4*)(x + i);
        f16x4 h;
        h[0] = (_Float16)v.x; h[1] = (_Float16)v.y;
        h[2] = (_Float16)v.z; h[3] = (_Float16)v.w;
        *(f16x4*)(Xh + i) = h;
        return;
    }
    __shared__ float tile[32][33];
    const float* in; _Float16* out; int C, bx, by;
    if (bid < 7872) {
        const int t = bid - 6144;            // 72 x 24 tiles
        in = Wqkv; out = Wqkvt; C = 2304;
        bx = (t % 72) * 32; by = (t / 72) * 32;
    } else {
        const int t = bid - 7872;            // 24 x 24 tiles
        in = Wout; out = Wot; C = 768;
        bx = (t % 24) * 32; by = (t / 24) * 32;
    }
    const int R = 768;
    const int tx = tid & 31, ty = tid >> 5;  // 32 x 8
#pragma unroll
    for (int j = 0; j < 32; j += 8)
        tile[ty + j][tx] = in[(size_t)(by + ty + j) * C + bx + tx];
    __syncthreads();
#pragma unroll
    for (int j = 0; j < 32; j += 8)
        out[(size_t)(bx + ty + j) * R + by + tx] = (_Float16)tile[tx][ty + j];
}

// ---------------- GEMM body: C[M][N] = A[M][K] * Bt[N][K]^T + bias ----------------
// 128x128 tile, BK=64, 256 threads = 4 waves, each wave 64x64. Exact-fit dims.
template <typename OutT>
__device__ __forceinline__ void gemm_body(const _Float16* __restrict__ A,
                                          const _Float16* __restrict__ Bt,
                                          const float* __restrict__ bias, bool bias_row,
                                          OutT* __restrict__ C, int N, int K,
                                          int m0, int n0,
                                          _Float16* As, _Float16* Bs) {
    const int tid  = threadIdx.x;
    const int wave = tid >> 6, lane = tid & 63, quad = lane >> 4, l16 = lane & 15;
    const int wm = (wave & 1) * 64, wn = (wave >> 1) * 64;
    const int rowc = lane >> 3, part = lane & 7;   // staging: 8 rows/chunk, 8 lanes/row

    f32x4 acc[4][4];
#pragma unroll
    for (int i = 0; i < 4; ++i)
#pragma unroll
        for (int n = 0; n < 4; ++n) acc[i][n] = f32x4{0.f, 0.f, 0.f, 0.f};

    for (int k0 = 0; k0 < K; k0 += 64) {
        __syncthreads();
#pragma unroll
        for (int cc = 0; cc < 4; ++cc) {
            const int ch = wave * 4 + cc;          // 16 chunks of 8 rows
            load16_to_lds(A  + (size_t)(m0 + ch * 8 + rowc) * K + k0 + part * 8,
                          As + ch * 512);
            load16_to_lds(Bt + (size_t)(n0 + ch * 8 + rowc) * K + k0 + part * 8,
                          Bs + ch * 512);
        }
        __syncthreads();
#pragma unroll
        for (int i = 0; i < 4; ++i) {
            f16x8 a0 = *(const f16x8*)(As + (wm + i * 16 + l16) * 64 + quad * 8);
            f16x8 a1 = *(const f16x8*)(As + (wm + i * 16 + l16) * 64 + 32 + quad * 8);
#pragma unroll
            for (int n = 0; n < 4; ++n) {
                f16x8 b0 = *(const f16x8*)(Bs + (wn + n * 16 + l16) * 64 + quad * 8);
                f16x8 b1 = *(const f16x8*)(Bs + (wn + n * 16 + l16) * 64 + 32 + quad * 8);
                acc[i][n] = __builtin_amdgcn_mfma_f32_16x16x32_f16(a0, b0, acc[i][n], 0, 0, 0);
                acc[i][n] = __builtin_amdgcn_mfma_f32_16x16x32_f16(a1, b1, acc[i][n], 0, 0, 0);
            }
        }
    }
#pragma unroll
    for (int i = 0; i < 4; ++i)
#pragma unroll
        for (int n = 0; n < 4; ++n)
#pragma unroll
            for (int r = 0; r < 4; ++r) {
                const int row = m0 + wm + i * 16 + quad * 4 + r;
                const int col = n0 + wn + n * 16 + l16;
                const float bv = bias_row ? bias[row] : bias[col];
                C[(size_t)row * N + col] = (OutT)(acc[i][n][r] + bv);
            }
}

// merged QK-projection + V^T-projection (independent, one launch, 1152 blocks)
__global__ __launch_bounds__(256) void gemm_qkv(const _Float16* __restrict__ Xh,
                                                const _Float16* __restrict__ Wqkvt,
                                                const float* __restrict__ bqkv,
                                                _Float16* __restrict__ QKh,
                                                _Float16* __restrict__ VtG) {
    __shared__ __align__(16) _Float16 As[128 * 64];
    __shared__ __align__(16) _Float16 Bs[128 * 64];
    const int bid = blockIdx.x;
    if (bid < 768) {       // QK: [8192][1536] = Xh . Wqkvt[0:1536]^T
        const int bx = bid % 12, by = bid / 12;
        gemm_body<_Float16>(Xh, Wqkvt, bqkv, false, QKh, 1536, DD,
                            by * 128, bx * 128, As, Bs);
    } else {               // V^T: [768][8192] = Wv^T . Xh^T
        const int t = bid - 768;
        const int bx = t % 64, by = t / 64;
        gemm_body<_Float16>(Wqkvt + (size_t)1536 * DD, Xh, bqkv + 1536, true, VtG,
                            8192, DD, by * 128, bx * 128, As, Bs);
    }
}

__global__ __launch_bounds__(256) void gemm_out(const _Float16* __restrict__ A,
                                                const _Float16* __restrict__ Bt,
                                                const float* __restrict__ bias,
                                                float* __restrict__ C) {
    __shared__ __align__(16) _Float16 As[128 * 64];
    __shared__ __align__(16) _Float16 Bs[128 * 64];
    gemm_body<float>(A, Bt, bias, false, C, DD, DD,
                     (int)blockIdx.y * 128, (int)blockIdx.x * 128, As, Bs);
}

// ---------------- flash attention: QBLK=128, uniform k-split blocks ----------------
// grid 768, 256 threads = 4 waves, 32 q-rows/wave (2 m-tiles).
//
// UNIFORM BLOCKS (this revision): R4's balanced-triples assumed round-robin
// block->CU assignment and was falsified (occupancy 37%->13%, 117 us). Now
// every block is IDENTICAL: 33 k-iters, as two segments -- half of tile a's
// k-range (a+1 iters) + half of tile (31-a)'s (32-a iters). LDS 48 KB forces
// exactly 3 blocks/CU (4th can't fit), so 768 uniform blocks balance
// perfectly under ANY assignment. No-max softmax makes k-split combining
// pure addition: each block stores raw f32 (O,l) partials to its own slot
// (slot = w, no conflict); per-tile flag via device atomicAdd; the SECOND
// arriver adds partner's partial in registers, divides, writes AOh.
//
// LDS-BW (R4 mechanism, kept): 32 rows/wave reuses each K/V fragment for two
// m-tiles -> ~56 KB LDS traffic per 64q x 64k unit (R3: 98 KB).
// PIPELINE (verified R10): QK(kt)/exp2/P(kt) overlap PV(kt-1); V staged one
// tile behind K. Ps single-buffer (wave-private, DS in-order).
// XCD-GROUP (verified R9: FETCH 200->20 MB): xcd = L&7 keeps each (b,h)
// group's K/V + partials in one XCD's L2.
// NO-MAX SOFTMAX (verified R5); sigma-permuted K rows; XOR chunk swizzles:
// 0 bank conflicts (verified R6-R8).
//
// qk: fp16 [B*T][1536] (Q at h*64, K at 768+h*64)
// vt: fp16 [768][8192]  (V^T: row h*64+d, col b*4096+t)
// ao: fp16 [B*T][768]
// Po: f32 [2][768][8192] raw O partials; Pl: f32 [2][768][128] raw l partials
// Fl: int[768] combine flags (zeroed in prep)
__global__ __launch_bounds__(256) void attn_kernel(const _Float16* __restrict__ qk,
                                                   const _Float16* __restrict__ vt,
                                                   _Float16* __restrict__ ao,
                                                   float* __restrict__ Po,
                                                   float* __restrict__ Pl,
                                                   int* __restrict__ Fl) {
    // LDS: Ks 2x8 KB + Vs 2x8 KB + Ps 4x4 KB = 49152 B -> 3 blocks/CU (forced).
    __shared__ __align__(16) _Float16 Ks[2][64 * 64];
    __shared__ __align__(16) _Float16 Vs[2][64 * 64];
    __shared__ __align__(16) _Float16 Ps[4][32 * 64];
    __shared__ int sFlag;

    // ---- decode: L in [0,768) -> (b, h, a, w). xcd = L&7 (group locality).
    // Block w of pair a handles: seg1 = tile a,    k in [w?(a+1):0, w?(2a+2):(a+1))
    //                            seg2 = tile 31-a, k in [w?0:(32-a), w?(32-a):(64-2a))
    const int L   = blockIdx.x;
    const int xcd = L & 7;
    const int r_  = L >> 3;          // 0..95
    const int gI  = r_ % 3;
    const int p   = r_ / 3;          // 0..31
    const int a   = p & 15;          // pair id 0..15
    const int w   = p >> 4;          // half id 0/1
    const int g   = gI * 8 + xcd;    // head-batch group 0..23
    const int b = g / NH, h = g % NH;

    const int tid = threadIdx.x;
    const int wave = tid >> 6, lane = tid & 63, quad = lane >> 4, l16 = lane & 15;

    f16x8 ones;
#pragma unroll
    for (int j = 0; j < 8; ++j) ones[j] = (_Float16)1.0f;

    // ---- per-lane 32-bit staging offsets (k0 added as uniform offset) ----
    int vK[2], vV[2];
#pragma unroll
    for (int pp = 0; pp < 2; ++pp) {
        const int j  = wave * 16 + pp * 8 + (lane >> 3);
        const int sig = (j & 15) * 4 + (j >> 4);        // sigma-permuted key
        const int cdk = (lane & 7) ^ (j & 7);           // swizzled source chunk
        vK[pp] = (b * TT + sig) * 1536 + DD + h * HDIM + cdk * 8;
        vV[pp] = (h * HDIM + j) * 8192 + b * TT + cdk * 8;
    }
    auto stageK = [&](int buf, int k0) {
        const int kK = k0 * 1536;   // uniform (SGPR) offset
#pragma unroll
        for (int pp = 0; pp < 2; ++pp)
            load16_to_lds(qk + (vK[pp] + kK), Ks[buf] + (wave * 16 + pp * 8) * 64);
    };
    auto stageV = [&](int buf, int k0) {
#pragma unroll
        for (int pp = 0; pp < 2; ++pp)
            load16_to_lds(vt + (vV[pp] + k0), Vs[buf] + (wave * 16 + pp * 8) * 64);
    };

    // ---- iter-invariant Ps addresses (stride 64, XOR swizzle, 0-conflict) ----
    _Float16* const PsW = &Ps[wave][0];
    _Float16* pw[2][4];       // write: row mq*16+quad*4+r, data cols l16*4..+3
#pragma unroll
    for (int mq = 0; mq < 2; ++mq)
#pragma unroll
        for (int r = 0; r < 4; ++r) {
            const int row = mq * 16 + quad * 4 + r;
            pw[mq][r] = PsW + row * 64 + (((l16 >> 1) ^ (row & 7)) * 8) + (l16 & 1) * 4;
        }
    const _Float16* pr[2][2]; // read: row mq*16+l16, logical cols kh*32+quad*8
#pragma unroll
    for (int mq = 0; mq < 2; ++mq)
#pragma unroll
        for (int kh = 0; kh < 2; ++kh)
            pr[mq][kh] = PsW + (mq * 16 + l16) * 64 + (((kh * 4 + quad) ^ (l16 & 7)) * 8);

    // ---- one k-segment of one q-tile, then partial handoff / combine ----
    auto seg = [&](int qt, int klo, int khi) {
        const int nkt = 2 * qt + 2;
        const int q0 = qt * 128;
        const int qrow0 = q0 + wave * 32;           // wave's first q-row
        f16x8 aq[2][2];
#pragma unroll
        for (int mq = 0; mq < 2; ++mq) {
            const int qoff = (b * TT + qrow0 + mq * 16 + l16) * 1536 + h * HDIM + quad * 8;
            const _Float16 sc = (_Float16)SC2;
            aq[mq][0] = *(const f16x8*)(qk + qoff) * sc;
            aq[mq][1] = *(const f16x8*)(qk + qoff + 32) * sc;
        }
        f32x4 o[2][4], lac[2];
#pragma unroll
        for (int mq = 0; mq < 2; ++mq) {
#pragma unroll
            for (int n = 0; n < 4; ++n) o[mq][n] = f32x4{0.f, 0.f, 0.f, 0.f};
            lac[mq] = f32x4{0.f, 0.f, 0.f, 0.f};
        }

        auto pv = [&](int vbuf) {
#pragma unroll
            for (int kh = 0; kh < 2; ++kh) {
                f16x8 ap0 = *(const f16x8*)pr[0][kh];
                f16x8 ap1 = *(const f16x8*)pr[1][kh];
                lac[0] = __builtin_amdgcn_mfma_f32_16x16x32_f16(ap0, ones, lac[0], 0, 0, 0);
                lac[1] = __builtin_amdgcn_mfma_f32_16x16x32_f16(ap1, ones, lac[1], 0, 0, 0);
#pragma unroll
                for (int n = 0; n < 4; ++n) {
                    const int posv = (kh * 4 + quad) ^ (l16 & 7);
                    f16x8 bv = *(const f16x8*)(Vs[vbuf] + (n * 16 + l16) * 64 + posv * 8);
                    o[0][n] = __builtin_amdgcn_mfma_f32_16x16x32_f16(ap0, bv, o[0][n], 0, 0, 0);
                    o[1][n] = __builtin_amdgcn_mfma_f32_16x16x32_f16(ap1, bv, o[1][n], 0, 0, 0);
                }
            }
        };

        stageK(0, klo * 64);      // prime: K only (V runs one tile behind)
        int cur = 0;
        for (int kt = klo; kt < khi; ++kt) {
            __syncthreads();      // drains vmcnt: K(kt) & V(kt-1) published
            if (kt + 1 < khi) stageK(cur ^ 1, (kt + 1) * 64);
            stageV(cur, kt * 64);

            __builtin_amdgcn_s_setprio(1);
            // ---- S = (Q*SC2) K^T (tile kt); bk reused for both m-tiles ----
            f32x4 s[2][4];
#pragma unroll
            for (int mq = 0; mq < 2; ++mq)
#pragma unroll
                for (int n = 0; n < 4; ++n) s[mq][n] = f32x4{0.f, 0.f, 0.f, 0.f};
#pragma unroll
            for (int kh = 0; kh < 2; ++kh)
#pragma unroll
                for (int n = 0; n < 4; ++n) {
                    const int pos = (kh * 4 + quad) ^ (l16 & 7);
                    f16x8 bk = *(const f16x8*)(Ks[cur] + (n * 16 + l16) * 64 + pos * 8);
                    s[0][n] = __builtin_amdgcn_mfma_f32_16x16x32_f16(aq[0][kh], bk, s[0][n], 0, 0, 0);
                    s[1][n] = __builtin_amdgcn_mfma_f32_16x16x32_f16(aq[1][kh], bk, s[1][n], 0, 0, 0);
                }

            // ---- O += P V ; l += P . 1 (tile kt-1: Ps reads precede the
            // exp2 overwrite below; DS executes in order within a wave) ----
            if (kt > klo) pv(cur ^ 1);
            __builtin_amdgcn_s_setprio(0);

            // ---- causal mask (absolute kt vs tile's nkt; covers qt=0) ----
            if (kt >= nkt - 2) {
#pragma unroll
                for (int mq = 0; mq < 2; ++mq) {
                    const int qr = qrow0 + mq * 16 + quad * 4;
#pragma unroll
                    for (int n = 0; n < 4; ++n) {
                        const int kg = kt * 64 + l16 * 4 + n;   // sigma: col -> key
#pragma unroll
                        for (int r = 0; r < 4; ++r)
                            if (kg > qr + r) s[mq][n][r] = -1e30f;
                    }
                }
            }

            // ---- P = exp2(s), single b64 store per (mq,r) ----
#pragma unroll
            for (int mq = 0; mq < 2; ++mq)
#pragma unroll
                for (int r = 0; r < 4; ++r) {
                    f16x4 pk;
#pragma unroll
                    for (int n = 0; n < 4; ++n)
                        pk[n] = (_Float16)__builtin_amdgcn_exp2f(s[mq][n][r]);
                    *(f16x4*)pw[mq][r] = pk;
                }
            cur ^= 1;
        }

        // ---- epilogue: PV of the last staged tile ----
        __syncthreads();
        pv(cur ^ 1);

        // ---- partial handoff: store raw (O,l) to MY slot (w), flag, and
        //      if I'm the second arriver: combine + finalize ----
        const int tIdx = g * 32 + qt;
        float* PoMe = Po + ((size_t)(w * 768 + tIdx)) * 8192;
        float* PlMe = Pl + (size_t)(w * 768 + tIdx) * 128;
#pragma unroll
        for (int mq = 0; mq < 2; ++mq) {
            if (l16 == 0)
                *(f32x4*)(PlMe + wave * 32 + mq * 16 + quad * 4) = lac[mq];
#pragma unroll
            for (int n = 0; n < 4; ++n)
                *(f32x4*)(PoMe + ((((wave * 2 + mq) * 4 + quad) * 4 + n) * 16 + l16) * 4) = o[mq][n];
        }
        __threadfence();          // publish partials before the flag
        __syncthreads();
        if (tid == 0) sFlag = atomicAdd(Fl + tIdx, 1);
        __syncthreads();
        if (sFlag == 1) {         // second arriver: partner's data is visible
            __threadfence();
            const float* PoPa = Po + ((size_t)((1 - w) * 768 + tIdx)) * 8192;
            const float* PlPa = Pl + (size_t)((1 - w) * 768 + tIdx) * 128;
#pragma unroll
            for (int mq = 0; mq < 2; ++mq) {
                f32x4 lp = *(const f32x4*)(PlPa + wave * 32 + mq * 16 + quad * 4);
                f32x4 lt = lac[mq] + lp;
                f32x4 inv;
#pragma unroll
                for (int r = 0; r < 4; ++r) inv[r] = 1.0f / lt[r];
#pragma unroll
                for (int n = 0; n < 4; ++n) {
                    f32x4 op = *(const f32x4*)(PoPa + ((((wave * 2 + mq) * 4 + quad) * 4 + n) * 16 + l16) * 4);
                    f32x4 ot = o[mq][n] + op;
#pragma unroll
                    for (int r = 0; r < 4; ++r) {
                        const int ooff = (b * TT + qrow0 + mq * 16 + quad * 4 + r) * DD + h * HDIM + l16;
                        ao[ooff + n * 16] = (_Float16)(ot[r] * inv[r]);
                    }
                }
            }
        }
    };

    // ---- two segments, 33 iters total (uniform for every block) ----
    if (w == 0) {
        seg(a, 0, a + 1);
        seg(31 - a, 32 - a, 64 - 2 * a);
    } else {
        seg(a, a + 1, 2 * a + 2);
        seg(31 - a, 0, 32 - a);
    }
}

// ---------------- launch ----------------
extern "C" void kernel_launch(void* const* d_in, const int* in_sizes, int n_in,
                              void* d_out, int out_size, void* d_ws, size_t ws_size,
                              hipStream_t stream) {
    const float* x     = (const float*)d_in[0];   // [2,4096,768]
    const float* Wqkv  = (const float*)d_in[1];   // [768,2304]
    const float* bqkv  = (const float*)d_in[2];   // [2304]
    const float* Wout  = (const float*)d_in[3];   // [768,768]
    const float* bout  = (const float*)d_in[4];   // [768]
    float* out = (float*)d_out;                   // [2,4096,768]

    // Layout: long-lived buffers first; Xh/Wqkvt (dead after gemm_qkv)
    // overlap the attn partial-O scratch Po. Total ws ~= 102.6 MB.
    char* ws = (char*)d_ws;
    _Float16* Wot   = (_Float16*)ws;  ws += (size_t)DD * DD * 2;         // 1.2 MB
    _Float16* QKh   = (_Float16*)ws;  ws += (size_t)BB * TT * 1536 * 2;  // 25.2 MB
    _Float16* VtG   = (_Float16*)ws;  ws += (size_t)DD * BB * TT * 2;    // 12.6 MB
    _Float16* AOh   = (_Float16*)ws;  ws += (size_t)BB * TT * DD * 2;    // 12.6 MB
    char* ovl = ws;                                                      // overlap region
    _Float16* Xh    = (_Float16*)ovl;                                    // 12.6 MB
    _Float16* Wqkvt = (_Float16*)(ovl + (size_t)BB * TT * DD * 2);       // +3.5 MB
    float*    Po    = (float*)ovl;    // 2*768*8192*4 = 50.3 MB (reuses Xh/Wqkvt)
    float*    Pl    = (float*)(ovl + (size_t)2 * 768 * 8192 * 4);        // 786 KB
    int*      Fl    = (int*)((char*)Pl + (size_t)2 * 768 * 128 * 4);     // 3 KB

    prep<<<8448, 256, 0, stream>>>(x, Xh, Wqkv, Wqkvt, Wout, Wot, Fl);

    gemm_qkv<<<1152, 256, 0, stream>>>(Xh, Wqkvt, bqkv, QKh, VtG);

    attn_kernel<<<768, 256, 0, stream>>>(QKh, VtG, AOh, Po, Pl, Fl);

    gemm_out<<<dim3(DD / 128, (BB * TT) / 128), 256, 0, stream>>>(AOh, Wot, bout, out);
}

// Round 6
// 245.816 us; speedup vs baseline: 2.1996x; 2.1996x over previous
//
#include <hip/hip_runtime.h>
#include <cstdint>
#include <cstddef>

// ---------------- types / helpers ----------------
typedef _Float16 f16x8 __attribute__((ext_vector_type(8)));
typedef _Float16 f16x4 __attribute__((ext_vector_type(4)));
typedef _Float16 f16x2 __attribute__((ext_vector_type(2)));
typedef float    f32x4 __attribute__((ext_vector_type(4)));

#define AS_GLOBAL __attribute__((address_space(1)))
#define AS_LDS    __attribute__((address_space(3)))

__device__ __forceinline__ void load16_to_lds(const _Float16* g, _Float16* l) {
    // async global->LDS, 16 B/lane, LDS dest = wave-uniform base + lane*16
    __builtin_amdgcn_global_load_lds((const AS_GLOBAL void*)g, (AS_LDS void*)l, 16, 0, 0);
}

// ---------------- problem constants ----------------
#define BB   2
#define TT   4096
#define DD   768
#define NH   12
#define HDIM 64
#define D3   2304
// softmax in exp2 domain: scale * log2(e), folded into Q at load
#define SC2  (0.125f * 1.44269504088896f)

// ---------------- merged prologue: cast + both transposes ----------------
__global__ __launch_bounds__(256) void prep(const float* __restrict__ x,
                                            _Float16* __restrict__ Xh,
                                            const float* __restrict__ Wqkv,
                                            _Float16* __restrict__ Wqkvt,
                                            const float* __restrict__ Wout,
                                            _Float16* __restrict__ Wot) {
    const int bid = blockIdx.x, tid = threadIdx.x;
    if (bid < 6144) {
        const int i = bid * 1024 + tid * 4;
        float4 v = *(const float4*)(x + i);
        f16x4 h;
        h[0] = (_Float16)v.x; h[1] = (_Float16)v.y;
        h[2] = (_Float16)v.z; h[3] = (_Float16)v.w;
        *(f16x4*)(Xh + i) = h;
        return;
    }
    __shared__ float tile[32][33];
    const float* in; _Float16* out; int C, bx, by;
    if (bid < 7872) {
        const int t = bid - 6144;            // 72 x 24 tiles
        in = Wqkv; out = Wqkvt; C = 2304;
        bx = (t % 72) * 32; by = (t / 72) * 32;
    } else {
        const int t = bid - 7872;            // 24 x 24 tiles
        in = Wout; out = Wot; C = 768;
        bx = (t % 24) * 32; by = (t / 24) * 32;
    }
    const int R = 768;
    const int tx = tid & 31, ty = tid >> 5;  // 32 x 8
#pragma unroll
    for (int j = 0; j < 32; j += 8)
        tile[ty + j][tx] = in[(size_t)(by + ty + j) * C + bx + tx];
    __syncthreads();
#pragma unroll
    for (int j = 0; j < 32; j += 8)
        out[(size_t)(bx + ty + j) * R + by + tx] = (_Float16)tile[tx][ty + j];
}

// ---------------- GEMM body: C[M][N] = A[M][K] * Bt[N][K]^T + bias ----------------
// 128x128 tile, BK=64, 256 threads = 4 waves, each wave 64x64. Exact-fit dims.
template <typename OutT>
__device__ __forceinline__ void gemm_body(const _Float16* __restrict__ A,
                                          const _Float16* __restrict__ Bt,
                                          const float* __restrict__ bias, bool bias_row,
                                          OutT* __restrict__ C, int N, int K,
                                          int m0, int n0,
                                          _Float16* As, _Float16* Bs) {
    const int tid  = threadIdx.x;
    const int wave = tid >> 6, lane = tid & 63, quad = lane >> 4, l16 = lane & 15;
    const int wm = (wave & 1) * 64, wn = (wave >> 1) * 64;
    const int rowc = lane >> 3, part = lane & 7;   // staging: 8 rows/chunk, 8 lanes/row

    f32x4 acc[4][4];
#pragma unroll
    for (int i = 0; i < 4; ++i)
#pragma unroll
        for (int n = 0; n < 4; ++n) acc[i][n] = f32x4{0.f, 0.f, 0.f, 0.f};

    for (int k0 = 0; k0 < K; k0 += 64) {
        __syncthreads();
#pragma unroll
        for (int cc = 0; cc < 4; ++cc) {
            const int ch = wave * 4 + cc;          // 16 chunks of 8 rows
            load16_to_lds(A  + (size_t)(m0 + ch * 8 + rowc) * K + k0 + part * 8,
                          As + ch * 512);
            load16_to_lds(Bt + (size_t)(n0 + ch * 8 + rowc) * K + k0 + part * 8,
                          Bs + ch * 512);
        }
        __syncthreads();
#pragma unroll
        for (int i = 0; i < 4; ++i) {
            f16x8 a0 = *(const f16x8*)(As + (wm + i * 16 + l16) * 64 + quad * 8);
            f16x8 a1 = *(const f16x8*)(As + (wm + i * 16 + l16) * 64 + 32 + quad * 8);
#pragma unroll
            for (int n = 0; n < 4; ++n) {
                f16x8 b0 = *(const f16x8*)(Bs + (wn + n * 16 + l16) * 64 + quad * 8);
                f16x8 b1 = *(const f16x8*)(Bs + (wn + n * 16 + l16) * 64 + 32 + quad * 8);
                acc[i][n] = __builtin_amdgcn_mfma_f32_16x16x32_f16(a0, b0, acc[i][n], 0, 0, 0);
                acc[i][n] = __builtin_amdgcn_mfma_f32_16x16x32_f16(a1, b1, acc[i][n], 0, 0, 0);
            }
        }
    }
#pragma unroll
    for (int i = 0; i < 4; ++i)
#pragma unroll
        for (int n = 0; n < 4; ++n)
#pragma unroll
            for (int r = 0; r < 4; ++r) {
                const int row = m0 + wm + i * 16 + quad * 4 + r;
                const int col = n0 + wn + n * 16 + l16;
                const float bv = bias_row ? bias[row] : bias[col];
                C[(size_t)row * N + col] = (OutT)(acc[i][n][r] + bv);
            }
}

// merged QK-projection + V^T-projection (independent, one launch, 1152 blocks)
__global__ __launch_bounds__(256) void gemm_qkv(const _Float16* __restrict__ Xh,
                                                const _Float16* __restrict__ Wqkvt,
                                                const float* __restrict__ bqkv,
                                                _Float16* __restrict__ QKh,
                                                _Float16* __restrict__ VtG) {
    __shared__ __align__(16) _Float16 As[128 * 64];
    __shared__ __align__(16) _Float16 Bs[128 * 64];
    const int bid = blockIdx.x;
    if (bid < 768) {       // QK: [8192][1536] = Xh . Wqkvt[0:1536]^T
        const int bx = bid % 12, by = bid / 12;
        gemm_body<_Float16>(Xh, Wqkvt, bqkv, false, QKh, 1536, DD,
                            by * 128, bx * 128, As, Bs);
    } else {               // V^T: [768][8192] = Wv^T . Xh^T
        const int t = bid - 768;
        const int bx = t % 64, by = t / 64;
        gemm_body<_Float16>(Wqkvt + (size_t)1536 * DD, Xh, bqkv + 1536, true, VtG,
                            8192, DD, by * 128, bx * 128, As, Bs);
    }
}

__global__ __launch_bounds__(256) void gemm_out(const _Float16* __restrict__ A,
                                                const _Float16* __restrict__ Bt,
                                                const float* __restrict__ bias,
                                                float* __restrict__ C) {
    __shared__ __align__(16) _Float16 As[128 * 64];
    __shared__ __align__(16) _Float16 Bs[128 * 64];
    gemm_body<float>(A, Bt, bias, false, C, DD, DD,
                     (int)blockIdx.y * 128, (int)blockIdx.x * 128, As, Bs);
}

// ---------------- flash attention: wave k-split on the R3 chassis ----------------
// grid 1536 (R3's PROVEN config: XCD-grouped, LPT heavy-first, 4 blocks/CU,
// measured 36.8% occ / 86.7 us), 256 threads = 4 waves. Each block: one 64-row
// q-tile qt, nkt = qt+1 k-iters.
//
// WAVE K-SPLIT (this revision): R3 was LDS-BW-bound because each of 4 waves
// read the FULL K,V tiles (~96 KB LDS traffic / 64q x 64k unit). Waves are now
// a 2x2 grid: wq = q-half (32 rows), wk = k-half (32 keys). Each K/V fragment
// is loaded once and reused for 2 m-tiles -> K reads 32->16 KB, V 32->16 KB
// per unit (total ~64 KB, -33%). Same MFMA count/wave. P stays WAVE-PRIVATE
// (each wave's P covers only its own 32 keys) so the verified single-Ps
// pipeline survives. k-half partials (o, lac) combine ONCE per block via LDS
// + 2 barriers -- no global traffic, no fences (R5's device-scope fences
// caused per-XCD L2 invalidation storms: 389 us, FETCH 2x).
//
// NEW K SIGMA: LDS row j holds key sig(j) = (j>>5)*32 + (j&15)*2 + ((j>>4)&1)
// (bijective). Then S-col l16 of n-tile n = wk*2+n' is key wk*32 + l16*2 + n',
// so wave wk's QK b-frags come only from Ks rows [wk*32, wk*32+32).
// V chunk select: logical key-chunk wk*4+quad, chunk-swizzled by row:
// posv = (wk*4+quad) ^ (l16&7) (Vs row d = n*16+l16, d&7 = l16&7).
// Ps: per-wave 32x32 fp16 (2 KB), 16B-chunk XOR swizzle phys = c ^ ((row>>2)&3):
// reads are full-width b128 (conflict-free minimum); writes 8x b32/iter at
// 4-way (negligible per m136).
//
// PIPELINE (verified R10): QK(kt)/exp2/P(kt) overlap PV(kt-1); V staged one
// tile behind K. XCD-GROUP (verified R9): xcd = L&7. NO-MAX SOFTMAX (R5-era,
// verified): P = exp2(s) directly, l via all-ones B-frag MFMA.
// LDS total: Ks 16 KB + Vs 16 KB + Ps 4 KB = 36 KB -> 4 blocks/CU.
//
// qk: fp16 [B*T][1536] (Q at h*64, K at 768+h*64)
// vt: fp16 [768][8192]  (V^T: row h*64+d, col b*4096+t)
// ao: fp16 [B*T][768]
__global__ __launch_bounds__(256) void attn_kernel(const _Float16* __restrict__ qk,
                                                   const _Float16* __restrict__ vt,
                                                   _Float16* __restrict__ ao) {
    __shared__ __align__(16) _Float16 Ks[2][64 * 64];
    __shared__ __align__(16) _Float16 Vs[2][64 * 64];
    __shared__ __align__(16) _Float16 Ps[4][32 * 32];

    // ---- decode: R3's exact LPT + XCD grouping (measured-good) ----
    const int L    = blockIdx.x;
    const int xcd  = L & 7;
    const int r_   = L >> 3;          // 0..191
    const int gIdx = r_ % 3;          // group on this XCD
    const int qt   = 63 - r_ / 3;     // heavy tiles dispatch first
    const int g    = gIdx * 8 + xcd;  // head-batch group 0..23
    const int b = g / NH, h = g % NH;

    const int tid = threadIdx.x;
    const int wave = tid >> 6, lane = tid & 63, quad = lane >> 4, l16 = lane & 15;
    const int wq = wave >> 1, wk = wave & 1;   // q-half, k-half

    f16x8 ones;
#pragma unroll
    for (int j = 0; j < 8; ++j) ones[j] = (_Float16)1.0f;

    // ---- per-lane 32-bit staging offsets (k0 added as uniform offset) ----
    int vK[2], vV[2];
#pragma unroll
    for (int p = 0; p < 2; ++p) {
        const int j   = wave * 16 + p * 8 + (lane >> 3);
        const int sig = (j >> 5) * 32 + (j & 15) * 2 + ((j >> 4) & 1);  // new sigma
        const int cdk = (lane & 7) ^ (j & 7);           // swizzled source chunk
        vK[p] = (b * TT + sig) * 1536 + DD + h * HDIM + cdk * 8;
        vV[p] = (h * HDIM + j) * 8192 + b * TT + cdk * 8;
    }
    auto stageK = [&](int buf, int k0) {
        const int kK = k0 * 1536;   // uniform (SGPR) offset
#pragma unroll
        for (int p = 0; p < 2; ++p)
            load16_to_lds(qk + (vK[p] + kK), Ks[buf] + (wave * 16 + p * 8) * 64);
    };
    auto stageV = [&](int buf, int k0) {
#pragma unroll
        for (int p = 0; p < 2; ++p)
            load16_to_lds(vt + (vV[p] + k0), Vs[buf] + (wave * 16 + p * 8) * 64);
    };

    // ---- Ps addresses: per-wave 32x32, 16B-chunk XOR swizzle ----
    _Float16* const PsW = &Ps[wave][0];
    _Float16* pw[2][4];       // write: row mq*16+quad*4+r, cols l16*2..+1 (f16x2)
#pragma unroll
    for (int mq = 0; mq < 2; ++mq)
#pragma unroll
        for (int r = 0; r < 4; ++r) {
            const int row = mq * 16 + quad * 4 + r;
            pw[mq][r] = PsW + row * 32 + (((l16 >> 2) ^ ((row >> 2) & 3)) * 8) + (l16 & 3) * 2;
        }
    const _Float16* pr[2];    // read: row mq*16+l16, logical chunk quad (keys quad*8..+8)
#pragma unroll
    for (int mq = 0; mq < 2; ++mq) {
        const int row = mq * 16 + l16;
        pr[mq] = PsW + row * 32 + ((quad ^ ((row >> 2) & 3)) * 8);
    }

    const int q0 = qt * 64;
    const int nkt = qt + 1;
    const int qrow0 = q0 + wq * 32;                 // wave's first q-row
    // Q a-frags, pre-scaled by SC2 (both wk waves of a wq load the same rows)
    f16x8 aq[2][2];
#pragma unroll
    for (int mq = 0; mq < 2; ++mq) {
        const int qoff = (b * TT + qrow0 + mq * 16 + l16) * 1536 + h * HDIM + quad * 8;
        const _Float16 sc = (_Float16)SC2;
        aq[mq][0] = *(const f16x8*)(qk + qoff) * sc;
        aq[mq][1] = *(const f16x8*)(qk + qoff + 32) * sc;
    }
    f32x4 o[2][4], lac[2];
#pragma unroll
    for (int mq = 0; mq < 2; ++mq) {
#pragma unroll
        for (int n = 0; n < 4; ++n) o[mq][n] = f32x4{0.f, 0.f, 0.f, 0.f};
        lac[mq] = f32x4{0.f, 0.f, 0.f, 0.f};
    }

    const int posv = (wk * 4 + quad) ^ (l16 & 7);   // wave's 32-key V chunks

    // PV of one tile: P (wave-private, 32 keys), V from Vs[vbuf].
    // ap loaded once per mq; bv loaded once per n, reused for both m-tiles.
    auto pv = [&](int vbuf) {
        f16x8 ap0 = *(const f16x8*)pr[0];
        f16x8 ap1 = *(const f16x8*)pr[1];
        lac[0] = __builtin_amdgcn_mfma_f32_16x16x32_f16(ap0, ones, lac[0], 0, 0, 0);
        lac[1] = __builtin_amdgcn_mfma_f32_16x16x32_f16(ap1, ones, lac[1], 0, 0, 0);
#pragma unroll
        for (int n = 0; n < 4; ++n) {
            f16x8 bv = *(const f16x8*)(Vs[vbuf] + (n * 16 + l16) * 64 + posv * 8);
            o[0][n] = __builtin_amdgcn_mfma_f32_16x16x32_f16(ap0, bv, o[0][n], 0, 0, 0);
            o[1][n] = __builtin_amdgcn_mfma_f32_16x16x32_f16(ap1, bv, o[1][n], 0, 0, 0);
        }
    };

    stageK(0, 0);             // prime: K tile 0 only (V runs one tile behind)
    int cur = 0;
    for (int kt = 0; kt < nkt; ++kt) {
        __syncthreads();      // drains vmcnt: K(kt) & V(kt-1) published
        if (kt + 1 < nkt) stageK(cur ^ 1, (kt + 1) * 64);
        stageV(cur, kt * 64);

        __builtin_amdgcn_s_setprio(1);
        // ---- S = (Q*SC2) K^T : wave's 2 n-tiles (keys wk*32..+32), depth 64 ----
        f32x4 s[2][2];
#pragma unroll
        for (int mq = 0; mq < 2; ++mq)
#pragma unroll
            for (int n1 = 0; n1 < 2; ++n1) s[mq][n1] = f32x4{0.f, 0.f, 0.f, 0.f};
#pragma unroll
        for (int kh = 0; kh < 2; ++kh)
#pragma unroll
            for (int n1 = 0; n1 < 2; ++n1) {
                const int rowK = (wk * 2 + n1) * 16 + l16;
                const int pos = (kh * 4 + quad) ^ (l16 & 7);
                f16x8 bk = *(const f16x8*)(Ks[cur] + rowK * 64 + pos * 8);
                s[0][n1] = __builtin_amdgcn_mfma_f32_16x16x32_f16(aq[0][kh], bk, s[0][n1], 0, 0, 0);
                s[1][n1] = __builtin_amdgcn_mfma_f32_16x16x32_f16(aq[1][kh], bk, s[1][n1], 0, 0, 0);
            }

        // ---- O += P V ; l += P . 1 (tile kt-1: Ps reads precede the exp2
        // overwrite below; DS executes in order within a wave) ----
        if (kt > 0) pv(cur ^ 1);
        __builtin_amdgcn_s_setprio(0);

        // ---- causal mask (diagonal tile only; both wk waves mask their keys) ----
        if (kt == nkt - 1) {
#pragma unroll
            for (int mq = 0; mq < 2; ++mq) {
                const int qr = qrow0 + mq * 16 + quad * 4;
#pragma unroll
                for (int n1 = 0; n1 < 2; ++n1) {
                    const int kg = kt * 64 + wk * 32 + l16 * 2 + n1;   // sigma: col -> key
#pragma unroll
                    for (int r = 0; r < 4; ++r)
                        if (kg > qr + r) s[mq][n1][r] = -1e30f;
                }
            }
        }

        // ---- P = exp2(s), one b32 store per (mq,r) ----
#pragma unroll
        for (int mq = 0; mq < 2; ++mq)
#pragma unroll
            for (int r = 0; r < 4; ++r) {
                f16x2 pk;
                pk[0] = (_Float16)__builtin_amdgcn_exp2f(s[mq][0][r]);
                pk[1] = (_Float16)__builtin_amdgcn_exp2f(s[mq][1][r]);
                *(f16x2*)pw[mq][r] = pk;
            }
        cur ^= 1;
    }

    // ---- epilogue: PV of the last tile (V(nkt-1) published by barrier) ----
    __syncthreads();
    pv(cur ^ 1);

    // ---- k-half combine via LDS (block-local, no fences): wk=1 waves park
    // (o, lac) in Ks/Ps (both dead now); wk=0 waves add, divide, store ----
    __syncthreads();          // all pv done (Ps/Vs reads complete)
    float* const Ksf = (float*)&Ks[0][0];   // 16 KB = 2 x 8 KB per wq
    float* const Psf = (float*)&Ps[0][0];   // lac scratch (first 256 B)
    if (wk) {
#pragma unroll
        for (int mq = 0; mq < 2; ++mq) {
            if (l16 == 0)
                *(f32x4*)(Psf + wq * 32 + mq * 16 + quad * 4) = lac[mq];
#pragma unroll
            for (int n = 0; n < 4; ++n)
                *(f32x4*)(Ksf + wq * 2048 + (mq * 4 + n) * 256 + lane * 4) = o[mq][n];
        }
    }
    __syncthreads();          // partials visible block-wide
    if (!wk) {
#pragma unroll
        for (int mq = 0; mq < 2; ++mq) {
            f32x4 lp = *(const f32x4*)(Psf + wq * 32 + mq * 16 + quad * 4);
            f32x4 inv;
#pragma unroll
            for (int r = 0; r < 4; ++r) inv[r] = 1.0f / (lac[mq][r] + lp[r]);
#pragma unroll
            for (int n = 0; n < 4; ++n) {
                f32x4 op = *(const f32x4*)(Ksf + wq * 2048 + (mq * 4 + n) * 256 + lane * 4);
#pragma unroll
                for (int r = 0; r < 4; ++r) {
                    const int ooff = (b * TT + qrow0 + mq * 16 + quad * 4 + r) * DD + h * HDIM + l16;
                    ao[ooff + n * 16] = (_Float16)((o[mq][n][r] + op[r]) * inv[r]);
                }
            }
        }
    }
}

// ---------------- launch ----------------
extern "C" void kernel_launch(void* const* d_in, const int* in_sizes, int n_in,
                              void* d_out, int out_size, void* d_ws, size_t ws_size,
                              hipStream_t stream) {
    const float* x     = (const float*)d_in[0];   // [2,4096,768]
    const float* Wqkv  = (const float*)d_in[1];   // [768,2304]
    const float* bqkv  = (const float*)d_in[2];   // [2304]
    const float* Wout  = (const float*)d_in[3];   // [768,768]
    const float* bout  = (const float*)d_in[4];   // [768]
    float* out = (float*)d_out;                   // [2,4096,768]

    char* ws = (char*)d_ws;
    _Float16* Xh    = (_Float16*)ws;  ws += (size_t)BB * TT * DD * 2;    // 12.6 MB
    _Float16* Wqkvt = (_Float16*)ws;  ws += (size_t)D3 * DD * 2;         // 3.5 MB
    _Float16* Wot   = (_Float16*)ws;  ws += (size_t)DD * DD * 2;         // 1.2 MB
    _Float16* QKh   = (_Float16*)ws;  ws += (size_t)BB * TT * 1536 * 2;  // 25.2 MB
    _Float16* VtG   = (_Float16*)ws;  ws += (size_t)DD * BB * TT * 2;    // 12.6 MB
    _Float16* AOh   = (_Float16*)ws;  ws += (size_t)BB * TT * DD * 2;    // 12.6 MB

    prep<<<8448, 256, 0, stream>>>(x, Xh, Wqkv, Wqkvt, Wout, Wot);

    gemm_qkv<<<1152, 256, 0, stream>>>(Xh, Wqkvt, bqkv, QKh, VtG);

    attn_kernel<<<1536, 256, 0, stream>>>(QKh, VtG, AOh);

    gemm_out<<<dim3(DD / 128, (BB * TT) / 128), 256, 0, stream>>>(AOh, Wot, bout, out);
}

// Round 8
// 241.247 us; speedup vs baseline: 2.2412x; 1.0189x over previous
//
#include <hip/hip_runtime.h>
#include <cstdint>
#include <cstddef>

// ---------------- types / helpers ----------------
typedef _Float16 f16x8 __attribute__((ext_vector_type(8)));
typedef _Float16 f16x4 __attribute__((ext_vector_type(4)));
typedef float    f32x4 __attribute__((ext_vector_type(4)));

#define AS_GLOBAL __attribute__((address_space(1)))
#define AS_LDS    __attribute__((address_space(3)))

__device__ __forceinline__ void load16_to_lds(const _Float16* g, _Float16* l) {
    // async global->LDS, 16 B/lane, LDS dest = wave-uniform base + lane*16
    __builtin_amdgcn_global_load_lds((const AS_GLOBAL void*)g, (AS_LDS void*)l, 16, 0, 0);
}

// ---------------- problem constants ----------------
#define BB   2
#define TT   4096
#define DD   768
#define NH   12
#define HDIM 64
#define D3   2304
// softmax in exp2 domain: scale * log2(e), folded into Q at load
#define SC2  (0.125f * 1.44269504088896f)

// ---------------- merged prologue: cast + both transposes ----------------
__global__ __launch_bounds__(256) void prep(const float* __restrict__ x,
                                            _Float16* __restrict__ Xh,
                                            const float* __restrict__ Wqkv,
                                            _Float16* __restrict__ Wqkvt,
                                            const float* __restrict__ Wout,
                                            _Float16* __restrict__ Wot) {
    const int bid = blockIdx.x, tid = threadIdx.x;
    if (bid < 6144) {
        const int i = bid * 1024 + tid * 4;
        float4 v = *(const float4*)(x + i);
        f16x4 h;
        h[0] = (_Float16)v.x; h[1] = (_Float16)v.y;
        h[2] = (_Float16)v.z; h[3] = (_Float16)v.w;
        *(f16x4*)(Xh + i) = h;
        return;
    }
    __shared__ float tile[32][33];
    const float* in; _Float16* out; int C, bx, by;
    if (bid < 7872) {
        const int t = bid - 6144;            // 72 x 24 tiles
        in = Wqkv; out = Wqkvt; C = 2304;
        bx = (t % 72) * 32; by = (t / 72) * 32;
    } else {
        const int t = bid - 7872;            // 24 x 24 tiles
        in = Wout; out = Wot; C = 768;
        bx = (t % 24) * 32; by = (t / 24) * 32;
    }
    const int R = 768;
    const int tx = tid & 31, ty = tid >> 5;  // 32 x 8
#pragma unroll
    for (int j = 0; j < 32; j += 8)
        tile[ty + j][tx] = in[(size_t)(by + ty + j) * C + bx + tx];
    __syncthreads();
#pragma unroll
    for (int j = 0; j < 32; j += 8)
        out[(size_t)(bx + ty + j) * R + by + tx] = (_Float16)tile[tx][ty + j];
}

// ---------------- GEMM body: C[M][N] = A[M][K] * Bt[N][K]^T + bias ----------------
// 128x128 tile, BK=64, 256 threads = 4 waves, each wave 64x64. Exact-fit dims.
template <typename OutT>
__device__ __forceinline__ void gemm_body(const _Float16* __restrict__ A,
                                          const _Float16* __restrict__ Bt,
                                          const float* __restrict__ bias, bool bias_row,
                                          OutT* __restrict__ C, int N, int K,
                                          int m0, int n0,
                                          _Float16* As, _Float16* Bs) {
    const int tid  = threadIdx.x;
    const int wave = tid >> 6, lane = tid & 63, quad = lane >> 4, l16 = lane & 15;
    const int wm = (wave & 1) * 64, wn = (wave >> 1) * 64;
    const int rowc = lane >> 3, part = lane & 7;   // staging: 8 rows/chunk, 8 lanes/row

    f32x4 acc[4][4];
#pragma unroll
    for (int i = 0; i < 4; ++i)
#pragma unroll
        for (int n = 0; n < 4; ++n) acc[i][n] = f32x4{0.f, 0.f, 0.f, 0.f};

    for (int k0 = 0; k0 < K; k0 += 64) {
        __syncthreads();
#pragma unroll
        for (int cc = 0; cc < 4; ++cc) {
            const int ch = wave * 4 + cc;          // 16 chunks of 8 rows
            load16_to_lds(A  + (size_t)(m0 + ch * 8 + rowc) * K + k0 + part * 8,
                          As + ch * 512);
            load16_to_lds(Bt + (size_t)(n0 + ch * 8 + rowc) * K + k0 + part * 8,
                          Bs + ch * 512);
        }
        __syncthreads();
#pragma unroll
        for (int i = 0; i < 4; ++i) {
            f16x8 a0 = *(const f16x8*)(As + (wm + i * 16 + l16) * 64 + quad * 8);
            f16x8 a1 = *(const f16x8*)(As + (wm + i * 16 + l16) * 64 + 32 + quad * 8);
#pragma unroll
            for (int n = 0; n < 4; ++n) {
                f16x8 b0 = *(const f16x8*)(Bs + (wn + n * 16 + l16) * 64 + quad * 8);
                f16x8 b1 = *(const f16x8*)(Bs + (wn + n * 16 + l16) * 64 + 32 + quad * 8);
                acc[i][n] = __builtin_amdgcn_mfma_f32_16x16x32_f16(a0, b0, acc[i][n], 0, 0, 0);
                acc[i][n] = __builtin_amdgcn_mfma_f32_16x16x32_f16(a1, b1, acc[i][n], 0, 0, 0);
            }
        }
    }
#pragma unroll
    for (int i = 0; i < 4; ++i)
#pragma unroll
        for (int n = 0; n < 4; ++n)
#pragma unroll
            for (int r = 0; r < 4; ++r) {
                const int row = m0 + wm + i * 16 + quad * 4 + r;
                const int col = n0 + wn + n * 16 + l16;
                const float bv = bias_row ? bias[row] : bias[col];
                C[(size_t)row * N + col] = (OutT)(acc[i][n][r] + bv);
            }
}

// merged QK-projection + V^T-projection (independent, one launch, 1152 blocks)
__global__ __launch_bounds__(256) void gemm_qkv(const _Float16* __restrict__ Xh,
                                                const _Float16* __restrict__ Wqkvt,
                                                const float* __restrict__ bqkv,
                                                _Float16* __restrict__ QKh,
                                                _Float16* __restrict__ VtG) {
    __shared__ __align__(16) _Float16 As[128 * 64];
    __shared__ __align__(16) _Float16 Bs[128 * 64];
    const int bid = blockIdx.x;
    if (bid < 768) {       // QK: [8192][1536] = Xh . Wqkvt[0:1536]^T
        const int bx = bid % 12, by = bid / 12;
        gemm_body<_Float16>(Xh, Wqkvt, bqkv, false, QKh, 1536, DD,
                            by * 128, bx * 128, As, Bs);
    } else {               // V^T: [768][8192] = Wv^T . Xh^T
        const int t = bid - 768;
        const int bx = t % 64, by = t / 64;
        gemm_body<_Float16>(Wqkvt + (size_t)1536 * DD, Xh, bqkv + 1536, true, VtG,
                            8192, DD, by * 128, bx * 128, As, Bs);
    }
}

__global__ __launch_bounds__(256) void gemm_out(const _Float16* __restrict__ A,
                                                const _Float16* __restrict__ Bt,
                                                const float* __restrict__ bias,
                                                float* __restrict__ C) {
    __shared__ __align__(16) _Float16 As[128 * 64];
    __shared__ __align__(16) _Float16 Bs[128 * 64];
    gemm_body<float>(A, Bt, bias, false, C, DD, DD,
                     (int)blockIdx.y * 128, (int)blockIdx.x * 128, As, Bs);
}

// ---------------- flash attention: swapped-QK^T, P in registers ----------------
// grid 1536 (R3's proven LPT + XCD grouping), 256 threads = 4 waves
// (wq = q-half of 32 rows, wk = k-half of 32 keys), one 64-row q-tile/block.
//
// SWAPPED QK^T (this revision): compute S^T = mfma(K_frag, Q_frag) -- A/B
// fragments of 16x16x32 have the SAME lane->data mapping, so the swap is free.
// Output: lane holds S[q=l16][key=quad*4+r]; exp2 of those 4 values is
// EXACTLY the A-fragment of mfma_f32_16x16x16f16 (A[i=l16][k=quad*4+0..3]),
// so P flows VGPR->VGPR into PV: the entire P LDS round-trip (store, load,
// swizzles -- R6's 4.79M bank conflicts) is deleted, along with the two-tile
// lag (chain is mfma->exp2->mfma in registers; TLP covers it). PV uses x16
// MFMAs (B: V[key quad*4+r][d=n*16+l16], ds_read_b64, <=2-way conflicts);
// l keeps the all-ones-B trick at x16. K staged with IDENTITY row order
// (sigma existed only for P-write contiguity). LDS 32 KB -> 5 blocks/CU
// (launch_bounds(256,5) holds VGPR <= 102).
//
// k-half combine ONCE per block via LDS park in dead Ks/Vs + 2 barriers
// (no fences -- R5's device-scope fences caused L2 invalidation storms).
// XCD-GROUP (verified R9): xcd = L&7. NO-MAX SOFTMAX (verified R5).
//
// qk: fp16 [B*T][1536] (Q at h*64, K at 768+h*64)
// vt: fp16 [768][8192]  (V^T: row h*64+d, col b*4096+t)
// ao: fp16 [B*T][768]
__global__ __launch_bounds__(256, 5) void attn_kernel(const _Float16* __restrict__ qk,
                                                      const _Float16* __restrict__ vt,
                                                      _Float16* __restrict__ ao) {
    __shared__ __align__(16) _Float16 Ks[2][64 * 64];
    __shared__ __align__(16) _Float16 Vs[2][64 * 64];

    // ---- decode: R3's exact LPT + XCD grouping (measured-good) ----
    const int L    = blockIdx.x;
    const int xcd  = L & 7;
    const int r_   = L >> 3;          // 0..191
    const int gIdx = r_ % 3;          // group on this XCD
    const int qt   = 63 - r_ / 3;     // heavy tiles dispatch first
    const int g    = gIdx * 8 + xcd;  // head-batch group 0..23
    const int b = g / NH, h = g % NH;

    const int tid = threadIdx.x;
    const int wave = tid >> 6, lane = tid & 63, quad = lane >> 4, l16 = lane & 15;
    const int wq = wave >> 1, wk = wave & 1;   // q-half, k-half

    f16x4 ones4;
#pragma unroll
    for (int j = 0; j < 4; ++j) ones4[j] = (_Float16)1.0f;

    // ---- per-lane 32-bit staging offsets (k0 added as uniform offset) ----
    // K rows: IDENTITY (LDS row j = key k0+j). 16B-chunk XOR swizzle by j&7.
    int vK[2], vV[2];
#pragma unroll
    for (int p = 0; p < 2; ++p) {
        const int j   = wave * 16 + p * 8 + (lane >> 3);
        const int cdk = (lane & 7) ^ (j & 7);           // swizzled source chunk
        vK[p] = (b * TT + j) * 1536 + DD + h * HDIM + cdk * 8;
        vV[p] = (h * HDIM + j) * 8192 + b * TT + cdk * 8;
    }
    auto stage = [&](int buf, int k0) {
        const int kK = k0 * 1536;   // uniform (SGPR) offsets
#pragma unroll
        for (int p = 0; p < 2; ++p) {
            load16_to_lds(qk + (vK[p] + kK), Ks[buf] + (wave * 16 + p * 8) * 64);
            load16_to_lds(vt + (vV[p] + k0), Vs[buf] + (wave * 16 + p * 8) * 64);
        }
    };

    const int q0 = qt * 64;
    const int nkt = qt + 1;
    const int qrow0 = q0 + wq * 32;                 // wave's first q-row
    const int qr_lane = qrow0 + l16;                // lane's q (S^T col); +16 for mq=1
    // Q fragments (B-operand of the swapped QK), pre-scaled by SC2
    f16x8 aq[2][2];
#pragma unroll
    for (int mq = 0; mq < 2; ++mq) {
        const int qoff = (b * TT + qrow0 + mq * 16 + l16) * 1536 + h * HDIM + quad * 8;
        const _Float16 sc = (_Float16)SC2;
        aq[mq][0] = *(const f16x8*)(qk + qoff) * sc;
        aq[mq][1] = *(const f16x8*)(qk + qoff + 32) * sc;
    }
    f32x4 o[2][4], lac[2];
#pragma unroll
    for (int mq = 0; mq < 2; ++mq) {
#pragma unroll
        for (int n = 0; n < 4; ++n) o[mq][n] = f32x4{0.f, 0.f, 0.f, 0.f};
        lac[mq] = f32x4{0.f, 0.f, 0.f, 0.f};
    }

    stage(0, 0);              // prime the pipeline
    int cur = 0;
    for (int kt = 0; kt < nkt; ++kt) {
        __syncthreads();      // drains vmcnt: tile kt published; other buf free
        if (kt + 1 < nkt) stage(cur ^ 1, (kt + 1) * 64);

        __builtin_amdgcn_s_setprio(1);
        // ---- S^T = K Q^T : wave's 32 keys x 32 q-rows, depth 64 ----
        // s[mq][n1]: lane holds S[q = qrow0+mq*16+l16][key = wk*32+n1*16+quad*4+r]
        f32x4 s[2][2];
#pragma unroll
        for (int mq = 0; mq < 2; ++mq)
#pragma unroll
            for (int n1 = 0; n1 < 2; ++n1) s[mq][n1] = f32x4{0.f, 0.f, 0.f, 0.f};
#pragma unroll
        for (int kh = 0; kh < 2; ++kh)
#pragma unroll
            for (int n1 = 0; n1 < 2; ++n1) {
                const int rowK = (wk * 2 + n1) * 16 + l16;          // key row (identity)
                const int pos = (kh * 4 + quad) ^ (l16 & 7);        // d-chunk swizzle
                f16x8 bk = *(const f16x8*)(Ks[cur] + rowK * 64 + pos * 8);
                s[0][n1] = __builtin_amdgcn_mfma_f32_16x16x32_f16(bk, aq[0][kh], s[0][n1], 0, 0, 0);
                s[1][n1] = __builtin_amdgcn_mfma_f32_16x16x32_f16(bk, aq[1][kh], s[1][n1], 0, 0, 0);
            }
        __builtin_amdgcn_s_setprio(0);

        // ---- causal mask (diagonal tile only) ----
        if (kt == nkt - 1) {
#pragma unroll
            for (int mq = 0; mq < 2; ++mq) {
                const int qr = qr_lane + mq * 16;
#pragma unroll
                for (int n1 = 0; n1 < 2; ++n1) {
                    const int kg0 = kt * 64 + wk * 32 + n1 * 16 + quad * 4;
#pragma unroll
                    for (int r = 0; r < 4; ++r)
                        if (kg0 + r > qr) s[mq][n1][r] = -1e30f;
                }
            }
        }

        // ---- P = exp2(S^T) directly into x16 A-fragments (VGPR only) ----
        f16x4 pa[2][2];
#pragma unroll
        for (int mq = 0; mq < 2; ++mq)
#pragma unroll
            for (int n1 = 0; n1 < 2; ++n1)
#pragma unroll
                for (int r = 0; r < 4; ++r)
                    pa[mq][n1][r] = (_Float16)__builtin_amdgcn_exp2f(s[mq][n1][r]);

        __builtin_amdgcn_s_setprio(1);
        // ---- l += P . 1 (x16, all-ones B; C rows = q = quad*4+r) ----
#pragma unroll
        for (int mq = 0; mq < 2; ++mq) {
            lac[mq] = __builtin_amdgcn_mfma_f32_16x16x16f16(pa[mq][0], ones4, lac[mq], 0, 0, 0);
            lac[mq] = __builtin_amdgcn_mfma_f32_16x16x16f16(pa[mq][1], ones4, lac[mq], 0, 0, 0);
        }
        // ---- O += P V (x16; B = V[key=quad*4+r][d=n*16+l16], b64 reads) ----
#pragma unroll
        for (int n1 = 0; n1 < 2; ++n1)
#pragma unroll
            for (int n = 0; n < 4; ++n) {
                const int rowV = n * 16 + l16;                       // d row
                const int lc  = wk * 4 + n1 * 2 + (quad >> 1);       // logical 16B chunk
                const int pc  = lc ^ (l16 & 7);                      // phys (stage swz)
                f16x4 bv = *(const f16x4*)(Vs[cur] + rowV * 64 + pc * 8 + (quad & 1) * 4);
                o[0][n] = __builtin_amdgcn_mfma_f32_16x16x16f16(pa[0][n1], bv, o[0][n], 0, 0, 0);
                o[1][n] = __builtin_amdgcn_mfma_f32_16x16x16f16(pa[1][n1], bv, o[1][n], 0, 0, 0);
            }
        __builtin_amdgcn_s_setprio(0);
        cur ^= 1;
    }

    // ---- k-half combine via LDS (block-local, no fences): wk=1 waves park
    // (o, lac) in dead Ks/Vs; wk=0 waves add, divide, store ----
    __syncthreads();          // all LDS reads of the loop complete
    float* const Ksf = (float*)&Ks[0][0];   // o scratch: 8 KB per wq
    float* const Vsf = (float*)&Vs[0][0];   // lac scratch (first 256 B)
    if (wk) {
#pragma unroll
        for (int mq = 0; mq < 2; ++mq) {
            if (l16 == 0)
                *(f32x4*)(Vsf + wq * 32 + mq * 16 + quad * 4) = lac[mq];
#pragma unroll
            for (int n = 0; n < 4; ++n)
                *(f32x4*)(Ksf + wq * 2048 + (mq * 4 + n) * 256 + lane * 4) = o[mq][n];
        }
    }
    __syncthreads();          // partials visible block-wide
    if (!wk) {
#pragma unroll
        for (int mq = 0; mq < 2; ++mq) {
            f32x4 lp = *(const f32x4*)(Vsf + wq * 32 + mq * 16 + quad * 4);
            f32x4 inv;
#pragma unroll
            for (int r = 0; r < 4; ++r) inv[r] = 1.0f / (lac[mq][r] + lp[r]);
#pragma unroll
            for (int n = 0; n < 4; ++n) {
                f32x4 op = *(const f32x4*)(Ksf + wq * 2048 + (mq * 4 + n) * 256 + lane * 4);
#pragma unroll
                for (int r = 0; r < 4; ++r) {
                    const int ooff = (b * TT + qrow0 + mq * 16 + quad * 4 + r) * DD + h * HDIM + l16;
                    ao[ooff + n * 16] = (_Float16)((o[mq][n][r] + op[r]) * inv[r]);
                }
            }
        }
    }
}

// ---------------- launch ----------------
extern "C" void kernel_launch(void* const* d_in, const int* in_sizes, int n_in,
                              void* d_out, int out_size, void* d_ws, size_t ws_size,
                              hipStream_t stream) {
    const float* x     = (const float*)d_in[0];   // [2,4096,768]
    const float* Wqkv  = (const float*)d_in[1];   // [768,2304]
    const float* bqkv  = (const float*)d_in[2];   // [2304]
    const float* Wout  = (const float*)d_in[3];   // [768,768]
    const float* bout  = (const float*)d_in[4];   // [768]
    float* out = (float*)d_out;                   // [2,4096,768]

    char* ws = (char*)d_ws;
    _Float16* Xh    = (_Float16*)ws;  ws += (size_t)BB * TT * DD * 2;    // 12.6 MB
    _Float16* Wqkvt = (_Float16*)ws;  ws += (size_t)D3 * DD * 2;         // 3.5 MB
    _Float16* Wot   = (_Float16*)ws;  ws += (size_t)DD * DD * 2;         // 1.2 MB
    _Float16* QKh   = (_Float16*)ws;  ws += (size_t)BB * TT * 1536 * 2;  // 25.2 MB
    _Float16* VtG   = (_Float16*)ws;  ws += (size_t)DD * BB * TT * 2;    // 12.6 MB
    _Float16* AOh   = (_Float16*)ws;  ws += (size_t)BB * TT * DD * 2;    // 12.6 MB

    prep<<<8448, 256, 0, stream>>>(x, Xh, Wqkv, Wqkvt, Wout, Wot);

    gemm_qkv<<<1152, 256, 0, stream>>>(Xh, Wqkvt, bqkv, QKh, VtG);

    attn_kernel<<<1536, 256, 0, stream>>>(QKh, VtG, AOh);

    gemm_out<<<dim3(DD / 128, (BB * TT) / 128), 256, 0, stream>>>(AOh, Wot, bout, out);
}